// Round 8
// baseline (570.206 us; speedup 1.0000x reference)
//
#include <hip/hip_runtime.h>
#include <math.h>

#define NA 10000
#define NE 250000
#define FD 128
#define NRBF 20
#define RCUT 5.0f

typedef _Float16 h16;
typedef __attribute__((ext_vector_type(8))) _Float16 half8;
typedef __attribute__((ext_vector_type(4))) _Float16 half4;
typedef __attribute__((ext_vector_type(4))) float f32x4;

static __device__ __forceinline__ half8 f32x8_to_h8(const float* p) {
    float4 a = *(const float4*)p;
    float4 b = *(const float4*)(p + 4);
    half8 r;
    r[0] = (h16)a.x; r[1] = (h16)a.y; r[2] = (h16)a.z; r[3] = (h16)a.w;
    r[4] = (h16)b.x; r[5] = (h16)b.y; r[6] = (h16)b.z; r[7] = (h16)b.w;
    return r;
}
static __device__ __forceinline__ float silu(float v) {
    return v / (1.f + expf(-v));
}

// ====== mega setup: geom | csr | weight transposes | filter prep ======
__global__ __launch_bounds__(256) void setup_kernel(
    const float* __restrict__ R, const int* __restrict__ idx_i,
    const int* __restrict__ idx_j, const float* __restrict__ offsets,
    float* __restrict__ dir, h16* __restrict__ ph, int* __restrict__ row_start,
    const float* __restrict__ int_W1, const float* __restrict__ int_W2,
    const float* __restrict__ mix_Wmu, const float* __restrict__ mix_W1,
    const float* __restrict__ mix_W2,
    h16* __restrict__ W1t, h16* __restrict__ W2t, h16* __restrict__ WmuT,
    h16* __restrict__ mW1t, h16* __restrict__ mW2t,
    const float* __restrict__ filt_W, const float* __restrict__ filt_b,
    h16* __restrict__ fwt)
{
    const int b = blockIdx.x;
    if (b < 977) {
        int e = b * 256 + threadIdx.x;
        if (e >= NE) return;
        int i = idx_i[e], j = idx_j[e];
        float rx = R[j * 3 + 0] - R[i * 3 + 0] + offsets[e * 3 + 0];
        float ry = R[j * 3 + 1] - R[i * 3 + 1] + offsets[e * 3 + 1];
        float rz = R[j * 3 + 2] - R[i * 3 + 2] + offsets[e * 3 + 2];
        float d = sqrtf(rx * rx + ry * ry + rz * rz);
        float inv = 1.f / d;
        float fcut = 0.f;
        if (d < RCUT) fcut = 0.5f * (cosf(d * (3.14159265358979323846f / RCUT)) + 1.f);
        *(float4*)&dir[(size_t)e * 4] = make_float4(rx * inv, ry * inv, rz * inv, 0.f);
        h16* pp = ph + (size_t)e * 32;
        const float delta = RCUT / 19.f;
        const float coeff = -0.5f / (delta * delta);
#pragma unroll
        for (int r = 0; r < NRBF; ++r) {
            float dc = d - (float)r * delta;
            pp[r] = (h16)(expf(coeff * dc * dc) * fcut);
        }
        pp[20] = (h16)fcut;
#pragma unroll
        for (int r = 21; r < 32; ++r) pp[r] = (h16)0.f;
    } else if (b < 1017) {
        int n = (b - 977) * 256 + threadIdx.x;
        if (n > NA) return;
        int lo = 0, hi = NE;
        while (lo < hi) {
            int mid = (lo + hi) >> 1;
            if (idx_i[mid] < n) lo = mid + 1; else hi = mid;
        }
        row_start[n] = lo;
    } else {
        int idx = (b - 1017) * 256 + threadIdx.x;
        if (idx < 49152) {                       // int_W1: K=128,N=128
            int bt = idx >> 14, rem = idx & 16383;
            int nn = rem >> 7, kk = rem & 127;
            W1t[idx] = (h16)int_W1[(size_t)bt * 16384 + kk * 128 + nn];
        } else if ((idx -= 49152) < 147456) {    // int_W2: K=128,N=384
            int bt = idx / 49152, rem = idx - bt * 49152;
            int nn = rem >> 7, kk = rem & 127;
            W2t[idx] = (h16)int_W2[(size_t)bt * 49152 + kk * 384 + nn];
        } else if ((idx -= 147456) < 98304) {    // mix_Wmu: K=128,N=256
            int bt = idx >> 15, rem = idx & 32767;
            int nn = rem >> 7, kk = rem & 127;
            WmuT[idx] = (h16)mix_Wmu[(size_t)bt * 32768 + kk * 256 + nn];
        } else if ((idx -= 98304) < 98304) {     // mix_W1: K=256,N=128
            int bt = idx >> 15, rem = idx & 32767;
            int nn = rem >> 8, kk = rem & 255;
            mW1t[idx] = (h16)mix_W1[(size_t)bt * 32768 + kk * 128 + nn];
        } else if ((idx -= 98304) < 147456) {    // mix_W2: K=128,N=384
            int bt = idx / 49152, rem = idx - bt * 49152;
            int nn = rem >> 7, kk = rem & 127;
            mW2t[idx] = (h16)mix_W2[(size_t)bt * 49152 + kk * 384 + nn];
        } else if ((idx -= 147456) < 12288) {    // fwt [384][32]
            int nn = idx >> 5, kk = idx & 31;
            float v = 0.f;
            if (kk < 20) v = filt_W[kk * 384 + nn];
            else if (kk == 20) v = filt_b[nn];
            fwt[idx] = (h16)v;
        }
    }
}

// ====== iteration-0 interaction MLP: q = emb[Z]; x16 = silu(q@W1+b1)@W2+b2 ==
__global__ __launch_bounds__(256) void intmlp0_kernel(
    const int* __restrict__ Z, const float* __restrict__ emb, float* __restrict__ q,
    const h16* __restrict__ W1t, const float* __restrict__ b1,
    const h16* __restrict__ W2t, const float* __restrict__ b2, h16* __restrict__ x16)
{
    __shared__ h16 Hs[16 * 136];
    const int tid = threadIdx.x;
    const int wave = tid >> 6, lane = tid & 63;
    const int ar = lane & 15, kg = lane >> 4;
    const size_t row0 = (size_t)blockIdx.x * 16;

    {
        int a = tid >> 4, f0 = (tid & 15) * 8;
        const float* src = emb + (size_t)Z[row0 + a] * 128 + f0;
        float4 v0 = *(const float4*)src;
        float4 v1 = *(const float4*)(src + 4);
        *(float4*)&q[(row0 + a) * 128 + f0] = v0;
        *(float4*)&q[(row0 + a) * 128 + f0 + 4] = v1;
    }
    const int zr = Z[row0 + ar];
    f32x4 a1[2] = {};
    for (int ks = 0; ks < 128; ks += 32) {
        int k = ks + kg * 8;
        half8 af = f32x8_to_h8(emb + (size_t)zr * 128 + k);
#pragma unroll
        for (int tt = 0; tt < 2; ++tt) {
            int t = wave * 2 + tt;
            half8 bf = *(const half8*)&W1t[(size_t)(t * 16 + ar) * 128 + k];
            a1[tt] = __builtin_amdgcn_mfma_f32_16x16x32_f16(af, bf, a1[tt], 0, 0, 0);
        }
    }
#pragma unroll
    for (int tt = 0; tt < 2; ++tt) {
        int col = (wave * 2 + tt) * 16 + ar;
        float bb = b1[col];
#pragma unroll
        for (int r = 0; r < 4; ++r)
            Hs[(kg * 4 + r) * 136 + col] = (h16)silu(a1[tt][r] + bb);
    }
    __syncthreads();
    f32x4 a2[6] = {};
    for (int ks = 0; ks < 128; ks += 32) {
        int k = ks + kg * 8;
        half8 af = *(const half8*)&Hs[ar * 136 + k];
#pragma unroll
        for (int tt = 0; tt < 6; ++tt) {
            int t = wave * 6 + tt;
            half8 bf = *(const half8*)&W2t[(size_t)(t * 16 + ar) * 128 + k];
            a2[tt] = __builtin_amdgcn_mfma_f32_16x16x32_f16(af, bf, a2[tt], 0, 0, 0);
        }
    }
#pragma unroll
    for (int tt = 0; tt < 6; ++tt) {
        int col = (wave * 6 + tt) * 16 + ar;
        float bb = b2[col];
#pragma unroll
        for (int r = 0; r < 4; ++r)
            x16[(row0 + kg * 4 + r) * 384 + col] = (h16)(a2[tt][r] + bb);
    }
}

// ====== edge kernel: transposed MFMA filter (A=fwt rows, B=ph cols) =========
// block = 1 atom, 4 waves; wave owns features [32w, 32w+32).
// C-layout: lane (kg,c) -> edge eg+c, features 16t+4kg+r (r contiguous!)
// => gathers are 8B dwordx2 loads; fwt A-fragments loaded once per block.
template<bool HAS_MU>
__global__ __launch_bounds__(256) void edge_kernel(
    const float* __restrict__ dir, const h16* __restrict__ ph,
    const h16* __restrict__ fwt,
    const int* __restrict__ row_start, const int* __restrict__ idx_j,
    const h16* __restrict__ x16, const h16* __restrict__ mu16p,
    const float* __restrict__ mup, float* __restrict__ mun,
    h16* __restrict__ mu16n, float* __restrict__ q)
{
    const int n = blockIdx.x, tid = threadIdx.x;
    const int wave = tid >> 6, lane = tid & 63;
    const int c = lane & 15, kg = lane >> 4;
    const int e0 = row_start[n], e1 = row_start[n + 1];
    const int f0 = wave * 32;

    // loop-invariant A fragments: feature rows of fwt for this wave
    half8 afq[2], afr[2], afm[2];
#pragma unroll
    for (int t = 0; t < 2; ++t) {
        int fr = f0 + 16 * t + c;
        afq[t] = *(const half8*)&fwt[(size_t)fr * 32 + kg * 8];
        afr[t] = *(const half8*)&fwt[(size_t)(128 + fr) * 32 + kg * 8];
        if (HAS_MU)
            afm[t] = *(const half8*)&fwt[(size_t)(256 + fr) * 32 + kg * 8];
    }

    f32x4 adq[2] = {}, am0[2] = {}, am1[2] = {}, am2[2] = {};

    if (e0 < e1) {
        // software pipeline: preload group 0
        int ec = e0 + c; int ecl = ec < e1 ? ec : e1 - 1;
        half8 bf = *(const half8*)&ph[(size_t)ecl * 32 + kg * 8];
        int j = idx_j[ecl];
        float4 g = *(const float4*)&dir[(size_t)ecl * 4];

        for (int eg = e0; eg < e1; eg += 16) {
            half8 bf_c = bf; int j_c = j; float4 g_c = g;
            bool v_c = (eg + c) < e1;
            int eg2 = eg + 16;
            if (eg2 < e1) {
                int e2 = eg2 + c; int ecl2 = e2 < e1 ? e2 : e1 - 1;
                bf = *(const half8*)&ph[(size_t)ecl2 * 32 + kg * 8];
                j = idx_j[ecl2];
                g = *(const float4*)&dir[(size_t)ecl2 * 4];
            }
            f32x4 z = {0.f, 0.f, 0.f, 0.f};
            f32x4 cwq[2], cwr[2], cwm[2];
#pragma unroll
            for (int t = 0; t < 2; ++t) {
                cwq[t] = __builtin_amdgcn_mfma_f32_16x16x32_f16(afq[t], bf_c, z, 0, 0, 0);
                cwr[t] = __builtin_amdgcn_mfma_f32_16x16x32_f16(afr[t], bf_c, z, 0, 0, 0);
                if (HAS_MU)
                    cwm[t] = __builtin_amdgcn_mfma_f32_16x16x32_f16(afm[t], bf_c, z, 0, 0, 0);
            }
            if (v_c) {
                const h16* xb = x16 + (size_t)j_c * 384;
#pragma unroll
                for (int t = 0; t < 2; ++t) {
                    int fb = f0 + 16 * t + kg * 4;
                    half4 x0 = *(const half4*)&xb[fb];
                    half4 x1 = *(const half4*)&xb[128 + fb];
                    half4 x2, m0, m1, m2;
                    if (HAS_MU) {
                        const h16* mb = mu16p + (size_t)j_c * 384;
                        x2 = *(const half4*)&xb[256 + fb];
                        m0 = *(const half4*)&mb[fb];
                        m1 = *(const half4*)&mb[128 + fb];
                        m2 = *(const half4*)&mb[256 + fb];
                    }
#pragma unroll
                    for (int r = 0; r < 4; ++r) {
                        adq[t][r] = fmaf(cwq[t][r], (float)x0[r], adq[t][r]);
                        float t1 = cwr[t][r] * (float)x1[r];
                        if (HAS_MU) {
                            float t2 = cwm[t][r] * (float)x2[r];
                            am0[t][r] += t1 * g_c.x + t2 * (float)m0[r];
                            am1[t][r] += t1 * g_c.y + t2 * (float)m1[r];
                            am2[t][r] += t1 * g_c.z + t2 * (float)m2[r];
                        } else {
                            am0[t][r] = fmaf(t1, g_c.x, am0[t][r]);
                            am1[t][r] = fmaf(t1, g_c.y, am1[t][r]);
                            am2[t][r] = fmaf(t1, g_c.z, am2[t][r]);
                        }
                    }
                }
            }
        }
    }

    // butterfly reduce across the 16 c-lanes
#pragma unroll
    for (int t = 0; t < 2; ++t)
#pragma unroll
        for (int r = 0; r < 4; ++r) {
            float a = adq[t][r], b0 = am0[t][r], b1 = am1[t][r], b2 = am2[t][r];
#pragma unroll
            for (int m = 1; m < 16; m <<= 1) {
                a  += __shfl_xor(a, m);
                b0 += __shfl_xor(b0, m);
                b1 += __shfl_xor(b1, m);
                b2 += __shfl_xor(b2, m);
            }
            adq[t][r] = a; am0[t][r] = b0; am1[t][r] = b1; am2[t][r] = b2;
        }

    if (c == 0) {
        size_t nb = (size_t)n * 384;
#pragma unroll
        for (int t = 0; t < 2; ++t) {
            int fb = f0 + 16 * t + kg * 4;
            float4 qv = *(float4*)&q[(size_t)n * 128 + fb];
            qv.x += adq[t][0]; qv.y += adq[t][1]; qv.z += adq[t][2]; qv.w += adq[t][3];
            *(float4*)&q[(size_t)n * 128 + fb] = qv;
            float4 p0, p1, p2;
            if (HAS_MU) {
                p0 = *(const float4*)&mup[nb + fb];
                p1 = *(const float4*)&mup[nb + 128 + fb];
                p2 = *(const float4*)&mup[nb + 256 + fb];
            } else {
                p0 = p1 = p2 = make_float4(0.f, 0.f, 0.f, 0.f);
            }
            p0.x += am0[t][0]; p0.y += am0[t][1]; p0.z += am0[t][2]; p0.w += am0[t][3];
            p1.x += am1[t][0]; p1.y += am1[t][1]; p1.z += am1[t][2]; p1.w += am1[t][3];
            p2.x += am2[t][0]; p2.y += am2[t][1]; p2.z += am2[t][2]; p2.w += am2[t][3];
            *(float4*)&mun[nb + fb] = p0;
            *(float4*)&mun[nb + 128 + fb] = p1;
            *(float4*)&mun[nb + 256 + fb] = p2;
            half4 h0 = {(h16)p0.x, (h16)p0.y, (h16)p0.z, (h16)p0.w};
            half4 h1 = {(h16)p1.x, (h16)p1.y, (h16)p1.z, (h16)p1.w};
            half4 h2 = {(h16)p2.x, (h16)p2.y, (h16)p2.z, (h16)p2.w};
            *(half4*)&mu16n[nb + fb] = h0;
            *(half4*)&mu16n[nb + 128 + fb] = h1;
            *(half4*)&mu16n[nb + 256 + fb] = h2;
        }
    }
}

// ====== fused mixing (+ optional next-iteration interaction MLP) ======
__global__ __launch_bounds__(256) void mixint_kernel(
    const h16* __restrict__ mu16n, const h16* __restrict__ WmuT,
    const h16* __restrict__ W1t, const float* __restrict__ b1,
    const h16* __restrict__ W2t, const float* __restrict__ b2,
    float* __restrict__ q, float* __restrict__ mu, h16* __restrict__ mu16w,
    const h16* __restrict__ nW1t, const float* __restrict__ nb1,
    const h16* __restrict__ nW2t, const float* __restrict__ nb2,
    h16* __restrict__ x16)
{
    __shared__ h16 MM[48 * 264];
    __shared__ h16 CT[16 * 264];
    __shared__ h16 Hs[16 * 136];
    __shared__ h16 XM[16 * 392];
    const int tid = threadIdx.x;
    const int wave = tid >> 6, lane = tid & 63;
    const int ar = lane & 15, kg = lane >> 4;
    const size_t row0 = (size_t)blockIdx.x * 16;

    {
        f32x4 acc[3][4] = {};
        int aloc[3], dloc[3];
#pragma unroll
        for (int rt = 0; rt < 3; ++rt) {
            int rr = rt * 16 + ar;
            aloc[rt] = rr / 3;
            dloc[rt] = rr - 3 * aloc[rt];
        }
        for (int ks = 0; ks < 128; ks += 32) {
            int k = ks + kg * 8;
            half8 afr[3];
#pragma unroll
            for (int rt = 0; rt < 3; ++rt)
                afr[rt] = *(const half8*)&mu16n[(row0 + aloc[rt]) * 384 + dloc[rt] * 128 + k];
#pragma unroll
            for (int ct = 0; ct < 4; ++ct) {
                int cc = wave * 4 + ct;
                half8 bf = *(const half8*)&WmuT[(size_t)(cc * 16 + ar) * 128 + k];
#pragma unroll
                for (int rt = 0; rt < 3; ++rt)
                    acc[rt][ct] = __builtin_amdgcn_mfma_f32_16x16x32_f16(afr[rt], bf, acc[rt][ct], 0, 0, 0);
            }
        }
#pragma unroll
        for (int rt = 0; rt < 3; ++rt)
#pragma unroll
            for (int ct = 0; ct < 4; ++ct) {
                int col = (wave * 4 + ct) * 16 + ar;
#pragma unroll
                for (int r = 0; r < 4; ++r)
                    MM[(rt * 16 + kg * 4 + r) * 264 + col] = (h16)acc[rt][ct][r];
            }
    }
    __syncthreads();

    {
        int a = tid >> 4, fi = (tid & 15) * 8;
        const float* qp = q + (row0 + a) * 128 + fi;
        float4 q0 = *(const float4*)qp;
        float4 q1 = *(const float4*)(qp + 4);
        float qv[8] = {q0.x, q0.y, q0.z, q0.w, q1.x, q1.y, q1.z, q1.w};
#pragma unroll
        for (int jj = 0; jj < 8; ++jj) {
            int ff = fi + jj;
            float v0 = (float)MM[(a * 3 + 0) * 264 + ff];
            float v1 = (float)MM[(a * 3 + 1) * 264 + ff];
            float v2 = (float)MM[(a * 3 + 2) * 264 + ff];
            CT[a * 264 + 128 + ff] = (h16)sqrtf(v0 * v0 + v1 * v1 + v2 * v2 + 1e-8f);
            CT[a * 264 + ff] = (h16)qv[jj];
        }
    }
    __syncthreads();

    {
        f32x4 a1[2] = {};
        for (int ks = 0; ks < 256; ks += 32) {
            int k = ks + kg * 8;
            half8 af = *(const half8*)&CT[ar * 264 + k];
#pragma unroll
            for (int tt = 0; tt < 2; ++tt) {
                int t = wave * 2 + tt;
                half8 bf = *(const half8*)&W1t[(size_t)(t * 16 + ar) * 256 + k];
                a1[tt] = __builtin_amdgcn_mfma_f32_16x16x32_f16(af, bf, a1[tt], 0, 0, 0);
            }
        }
#pragma unroll
        for (int tt = 0; tt < 2; ++tt) {
            int col = (wave * 2 + tt) * 16 + ar;
            float bb = b1[col];
#pragma unroll
            for (int r = 0; r < 4; ++r)
                Hs[(kg * 4 + r) * 136 + col] = (h16)silu(a1[tt][r] + bb);
        }
    }
    __syncthreads();

    {
        f32x4 a2[6] = {};
        for (int ks = 0; ks < 128; ks += 32) {
            int k = ks + kg * 8;
            half8 af = *(const half8*)&Hs[ar * 136 + k];
#pragma unroll
            for (int tt = 0; tt < 6; ++tt) {
                int t = wave * 6 + tt;
                half8 bf = *(const half8*)&W2t[(size_t)(t * 16 + ar) * 128 + k];
                a2[tt] = __builtin_amdgcn_mfma_f32_16x16x32_f16(af, bf, a2[tt], 0, 0, 0);
            }
        }
#pragma unroll
        for (int tt = 0; tt < 6; ++tt) {
            int col = (wave * 6 + tt) * 16 + ar;
            float bb = b2[col];
#pragma unroll
            for (int r = 0; r < 4; ++r)
                XM[(kg * 4 + r) * 392 + col] = (h16)(a2[tt][r] + bb);
        }
    }
    __syncthreads();

    {
        int a = tid >> 4, fi = (tid & 15) * 8;
        size_t n = row0 + a;
#pragma unroll
        for (int jj = 0; jj < 8; ++jj) {
            int ff = fi + jj;
            float dq  = (float)XM[a * 392 + ff];
            float dm  = (float)XM[a * 392 + 128 + ff];
            float dqm = (float)XM[a * 392 + 256 + ff];
            float v0 = (float)MM[(a * 3 + 0) * 264 + ff], w0 = (float)MM[(a * 3 + 0) * 264 + 128 + ff];
            float v1 = (float)MM[(a * 3 + 1) * 264 + ff], w1 = (float)MM[(a * 3 + 1) * 264 + 128 + ff];
            float v2 = (float)MM[(a * 3 + 2) * 264 + ff], w2 = (float)MM[(a * 3 + 2) * 264 + 128 + ff];
            float sv = v0 * w0 + v1 * w1 + v2 * w2;
            float qn = q[n * 128 + ff] + dq + dqm * sv;
            q[n * 128 + ff] = qn;
            CT[a * 264 + ff] = (h16)qn;
            size_t b = n * 384 + ff;
            float m0 = mu[b] + dm * w0;
            float m1 = mu[b + 128] + dm * w1;
            float m2 = mu[b + 256] + dm * w2;
            mu[b] = m0; mu[b + 128] = m1; mu[b + 256] = m2;
            mu16w[b] = (h16)m0; mu16w[b + 128] = (h16)m1; mu16w[b + 256] = (h16)m2;
        }
    }
    if (!nW1t) return;
    __syncthreads();

    {
        f32x4 a1[2] = {};
        for (int ks = 0; ks < 128; ks += 32) {
            int k = ks + kg * 8;
            half8 af = *(const half8*)&CT[ar * 264 + k];
#pragma unroll
            for (int tt = 0; tt < 2; ++tt) {
                int t = wave * 2 + tt;
                half8 bf = *(const half8*)&nW1t[(size_t)(t * 16 + ar) * 128 + k];
                a1[tt] = __builtin_amdgcn_mfma_f32_16x16x32_f16(af, bf, a1[tt], 0, 0, 0);
            }
        }
#pragma unroll
        for (int tt = 0; tt < 2; ++tt) {
            int col = (wave * 2 + tt) * 16 + ar;
            float bb = nb1[col];
#pragma unroll
            for (int r = 0; r < 4; ++r)
                Hs[(kg * 4 + r) * 136 + col] = (h16)silu(a1[tt][r] + bb);
        }
        __syncthreads();
        f32x4 a2[6] = {};
        for (int ks = 0; ks < 128; ks += 32) {
            int k = ks + kg * 8;
            half8 af = *(const half8*)&Hs[ar * 136 + k];
#pragma unroll
            for (int tt = 0; tt < 6; ++tt) {
                int t = wave * 6 + tt;
                half8 bf = *(const half8*)&nW2t[(size_t)(t * 16 + ar) * 128 + k];
                a2[tt] = __builtin_amdgcn_mfma_f32_16x16x32_f16(af, bf, a2[tt], 0, 0, 0);
            }
        }
#pragma unroll
        for (int tt = 0; tt < 6; ++tt) {
            int col = (wave * 6 + tt) * 16 + ar;
            float bb = nb2[col];
#pragma unroll
            for (int r = 0; r < 4; ++r)
                x16[(row0 + kg * 4 + r) * 384 + col] = (h16)(a2[tt][r] + bb);
        }
    }
}

// ====== launch ======
extern "C" void kernel_launch(void* const* d_in, const int* in_sizes, int n_in,
                              void* d_out, int out_size, void* d_ws, size_t ws_size,
                              hipStream_t stream)
{
    const int*   Z       = (const int*)d_in[0];
    const float* R       = (const float*)d_in[1];
    const int*   idx_i   = (const int*)d_in[2];
    const int*   idx_j   = (const int*)d_in[3];
    const float* offsets = (const float*)d_in[4];
    const float* emb     = (const float*)d_in[5];
    const float* filt_W  = (const float*)d_in[6];
    const float* filt_b  = (const float*)d_in[7];
    const float* int_W1  = (const float*)d_in[8];
    const float* int_b1  = (const float*)d_in[9];
    const float* int_W2  = (const float*)d_in[10];
    const float* int_b2  = (const float*)d_in[11];
    const float* mix_Wmu = (const float*)d_in[12];
    const float* mix_W1  = (const float*)d_in[13];
    const float* mix_b1  = (const float*)d_in[14];
    const float* mix_W2  = (const float*)d_in[15];
    const float* mix_b2  = (const float*)d_in[16];

    float* q_out  = (float*)d_out;
    float* mu_out = (float*)d_out + (size_t)NA * FD;

    char* base = (char*)d_ws;
    size_t o = 0;
    auto alloc = [&](size_t bytes) -> void* {
        void* p = base + o;
        o += (bytes + 255) & ~(size_t)255;
        return p;
    };
    float* dir    = (float*)alloc((size_t)NE * 4 * 4);
    h16*   ph     = (h16*)alloc((size_t)NE * 32 * 2);
    h16*   x16    = (h16*)alloc((size_t)NA * 384 * 2);
    h16*   mu16a  = (h16*)alloc((size_t)NA * 384 * 2);
    h16*   mu16b  = (h16*)alloc((size_t)NA * 384 * 2);
    float* mu_ws  = (float*)alloc((size_t)NA * 384 * 4);
    h16*   W1t    = (h16*)alloc((size_t)3 * 128 * 128 * 2);
    h16*   W2t    = (h16*)alloc((size_t)3 * 384 * 128 * 2);
    h16*   WmuT   = (h16*)alloc((size_t)3 * 256 * 128 * 2);
    h16*   mW1t   = (h16*)alloc((size_t)3 * 128 * 256 * 2);
    h16*   mW2t   = (h16*)alloc((size_t)3 * 384 * 128 * 2);
    h16*   fwt    = (h16*)alloc((size_t)384 * 32 * 2);
    int*   row_st = (int*)alloc((size_t)(NA + 1) * 4);

    setup_kernel<<<3177, 256, 0, stream>>>(R, idx_i, idx_j, offsets, dir, ph, row_st,
                                           int_W1, int_W2, mix_Wmu, mix_W1, mix_W2,
                                           W1t, W2t, WmuT, mW1t, mW2t,
                                           filt_W, filt_b, fwt);

    // iteration 0
    intmlp0_kernel<<<NA / 16, 256, 0, stream>>>(Z, emb, q_out,
                                                W1t, int_b1, W2t, int_b2, x16);
    edge_kernel<false><<<NA, 256, 0, stream>>>(dir, ph, fwt, row_st, idx_j,
                                               x16, nullptr, nullptr, mu_out, mu16b, q_out);
    mixint_kernel<<<NA / 16, 256, 0, stream>>>(
        mu16b, WmuT, mW1t, mix_b1, mW2t, mix_b2, q_out, mu_out, mu16b,
        W1t + 16384, int_b1 + 128, W2t + 49152, int_b2 + 384, x16);

    // iteration 1
    edge_kernel<true><<<NA, 256, 0, stream>>>(dir, ph, fwt, row_st, idx_j,
                                              x16, mu16b, mu_out, mu_ws, mu16a, q_out);
    mixint_kernel<<<NA / 16, 256, 0, stream>>>(
        mu16a, WmuT + 32768, mW1t + 32768, mix_b1 + 128, mW2t + 49152, mix_b2 + 384,
        q_out, mu_ws, mu16a,
        W1t + 32768, int_b1 + 256, W2t + 98304, int_b2 + 768, x16);

    // iteration 2
    edge_kernel<true><<<NA, 256, 0, stream>>>(dir, ph, fwt, row_st, idx_j,
                                              x16, mu16a, mu_ws, mu_out, mu16b, q_out);
    mixint_kernel<<<NA / 16, 256, 0, stream>>>(
        mu16b, WmuT + 65536, mW1t + 65536, mix_b1 + 256, mW2t + 98304, mix_b2 + 768,
        q_out, mu_out, mu16b,
        nullptr, nullptr, nullptr, nullptr, nullptr);
}

// Round 9
// 443.823 us; speedup vs baseline: 1.2848x; 1.2848x over previous
//
#include <hip/hip_runtime.h>
#include <math.h>

#define NA 10000
#define NE 250000
#define FD 128
#define NRBF 20
#define RCUT 5.0f

typedef _Float16 h16;
typedef __attribute__((ext_vector_type(8))) _Float16 half8;
typedef __attribute__((ext_vector_type(2))) _Float16 half2v;
typedef __attribute__((ext_vector_type(4))) float f32x4;

static __device__ __forceinline__ half8 f32x8_to_h8(const float* p) {
    float4 a = *(const float4*)p;
    float4 b = *(const float4*)(p + 4);
    half8 r;
    r[0] = (h16)a.x; r[1] = (h16)a.y; r[2] = (h16)a.z; r[3] = (h16)a.w;
    r[4] = (h16)b.x; r[5] = (h16)b.y; r[6] = (h16)b.z; r[7] = (h16)b.w;
    return r;
}
static __device__ __forceinline__ float silu(float v) {
    return v / (1.f + expf(-v));
}

// ====== mega setup: geom | csr | weight transposes | filter prep ======
__global__ __launch_bounds__(256) void setup_kernel(
    const float* __restrict__ R, const int* __restrict__ idx_i,
    const int* __restrict__ idx_j, const float* __restrict__ offsets,
    float* __restrict__ dir, h16* __restrict__ ph, int* __restrict__ row_start,
    const float* __restrict__ int_W1, const float* __restrict__ int_W2,
    const float* __restrict__ mix_Wmu, const float* __restrict__ mix_W1,
    const float* __restrict__ mix_W2,
    h16* __restrict__ W1t, h16* __restrict__ W2t, h16* __restrict__ WmuT,
    h16* __restrict__ mW1t, h16* __restrict__ mW2t,
    const float* __restrict__ filt_W, const float* __restrict__ filt_b,
    h16* __restrict__ fwt)
{
    const int b = blockIdx.x;
    if (b < 977) {
        int e = b * 256 + threadIdx.x;
        if (e >= NE) return;
        int i = idx_i[e], j = idx_j[e];
        float rx = R[j * 3 + 0] - R[i * 3 + 0] + offsets[e * 3 + 0];
        float ry = R[j * 3 + 1] - R[i * 3 + 1] + offsets[e * 3 + 1];
        float rz = R[j * 3 + 2] - R[i * 3 + 2] + offsets[e * 3 + 2];
        float d = sqrtf(rx * rx + ry * ry + rz * rz);
        float inv = 1.f / d;
        float fcut = 0.f;
        if (d < RCUT) fcut = 0.5f * (cosf(d * (3.14159265358979323846f / RCUT)) + 1.f);
        *(float4*)&dir[(size_t)e * 4] = make_float4(rx * inv, ry * inv, rz * inv, 0.f);
        h16* pp = ph + (size_t)e * 32;
        const float delta = RCUT / 19.f;
        const float coeff = -0.5f / (delta * delta);
#pragma unroll
        for (int r = 0; r < NRBF; ++r) {
            float dc = d - (float)r * delta;
            pp[r] = (h16)(expf(coeff * dc * dc) * fcut);
        }
        pp[20] = (h16)fcut;
#pragma unroll
        for (int r = 21; r < 32; ++r) pp[r] = (h16)0.f;
    } else if (b < 1017) {
        int n = (b - 977) * 256 + threadIdx.x;
        if (n > NA) return;
        int lo = 0, hi = NE;
        while (lo < hi) {
            int mid = (lo + hi) >> 1;
            if (idx_i[mid] < n) lo = mid + 1; else hi = mid;
        }
        row_start[n] = lo;
    } else {
        int idx = (b - 1017) * 256 + threadIdx.x;
        if (idx < 49152) {                       // int_W1: K=128,N=128
            int bt = idx >> 14, rem = idx & 16383;
            int nn = rem >> 7, kk = rem & 127;
            W1t[idx] = (h16)int_W1[(size_t)bt * 16384 + kk * 128 + nn];
        } else if ((idx -= 49152) < 147456) {    // int_W2: K=128,N=384
            int bt = idx / 49152, rem = idx - bt * 49152;
            int nn = rem >> 7, kk = rem & 127;
            W2t[idx] = (h16)int_W2[(size_t)bt * 49152 + kk * 384 + nn];
        } else if ((idx -= 147456) < 98304) {    // mix_Wmu: K=128,N=256
            int bt = idx >> 15, rem = idx & 32767;
            int nn = rem >> 7, kk = rem & 127;
            WmuT[idx] = (h16)mix_Wmu[(size_t)bt * 32768 + kk * 256 + nn];
        } else if ((idx -= 98304) < 98304) {     // mix_W1: K=256,N=128
            int bt = idx >> 15, rem = idx & 32767;
            int nn = rem >> 8, kk = rem & 255;
            mW1t[idx] = (h16)mix_W1[(size_t)bt * 32768 + kk * 128 + nn];
        } else if ((idx -= 98304) < 147456) {    // mix_W2: K=128,N=384
            int bt = idx / 49152, rem = idx - bt * 49152;
            int nn = rem >> 7, kk = rem & 127;
            mW2t[idx] = (h16)mix_W2[(size_t)bt * 49152 + kk * 384 + nn];
        } else if ((idx -= 147456) < 12288) {    // fwt [384][32]
            int nn = idx >> 5, kk = idx & 31;
            float v = 0.f;
            if (kk < 20) v = filt_W[kk * 384 + nn];
            else if (kk == 20) v = filt_b[nn];
            fwt[idx] = (h16)v;
        }
    }
}

// ====== iteration-0 interaction MLP: q = emb[Z]; x16 = silu(q@W1+b1)@W2+b2 ==
__global__ __launch_bounds__(256) void intmlp0_kernel(
    const int* __restrict__ Z, const float* __restrict__ emb, float* __restrict__ q,
    const h16* __restrict__ W1t, const float* __restrict__ b1,
    const h16* __restrict__ W2t, const float* __restrict__ b2, h16* __restrict__ x16)
{
    __shared__ h16 Hs[16 * 136];
    const int tid = threadIdx.x;
    const int wave = tid >> 6, lane = tid & 63;
    const int ar = lane & 15, kg = lane >> 4;
    const size_t row0 = (size_t)blockIdx.x * 16;

    {
        int a = tid >> 4, f0 = (tid & 15) * 8;
        const float* src = emb + (size_t)Z[row0 + a] * 128 + f0;
        float4 v0 = *(const float4*)src;
        float4 v1 = *(const float4*)(src + 4);
        *(float4*)&q[(row0 + a) * 128 + f0] = v0;
        *(float4*)&q[(row0 + a) * 128 + f0 + 4] = v1;
    }
    const int zr = Z[row0 + ar];
    f32x4 a1[2] = {};
    for (int ks = 0; ks < 128; ks += 32) {
        int k = ks + kg * 8;
        half8 af = f32x8_to_h8(emb + (size_t)zr * 128 + k);
#pragma unroll
        for (int tt = 0; tt < 2; ++tt) {
            int t = wave * 2 + tt;
            half8 bf = *(const half8*)&W1t[(size_t)(t * 16 + ar) * 128 + k];
            a1[tt] = __builtin_amdgcn_mfma_f32_16x16x32_f16(af, bf, a1[tt], 0, 0, 0);
        }
    }
#pragma unroll
    for (int tt = 0; tt < 2; ++tt) {
        int col = (wave * 2 + tt) * 16 + ar;
        float bb = b1[col];
#pragma unroll
        for (int r = 0; r < 4; ++r)
            Hs[(kg * 4 + r) * 136 + col] = (h16)silu(a1[tt][r] + bb);
    }
    __syncthreads();
    f32x4 a2[6] = {};
    for (int ks = 0; ks < 128; ks += 32) {
        int k = ks + kg * 8;
        half8 af = *(const half8*)&Hs[ar * 136 + k];
#pragma unroll
        for (int tt = 0; tt < 6; ++tt) {
            int t = wave * 6 + tt;
            half8 bf = *(const half8*)&W2t[(size_t)(t * 16 + ar) * 128 + k];
            a2[tt] = __builtin_amdgcn_mfma_f32_16x16x32_f16(af, bf, a2[tt], 0, 0, 0);
        }
    }
#pragma unroll
    for (int tt = 0; tt < 6; ++tt) {
        int col = (wave * 6 + tt) * 16 + ar;
        float bb = b2[col];
#pragma unroll
        for (int r = 0; r < 4; ++r)
            x16[(row0 + kg * 4 + r) * 384 + col] = (h16)(a2[tt][r] + bb);
    }
}

// ====== edge kernel (R4 structure: lane = feature, serial edges) ======
// One block per atom, 128 threads. Filter as packed-f16 FMA against
// register-cached fwt columns; all gathers are wave-coalesced (one row,
// 128 contiguous lanes). Measured: this layout is at its VALU floor and
// beats all MFMA-filter variants (R5/R7/R8) on latency+coalescing.
template<bool HAS_MU>
__global__ __launch_bounds__(128) void edge_kernel(
    const float* __restrict__ dir, const h16* __restrict__ ph,
    const h16* __restrict__ fwt,
    const int* __restrict__ row_start, const int* __restrict__ idx_j,
    const h16* __restrict__ x16, const h16* __restrict__ mu16p,
    const float* __restrict__ mup, float* __restrict__ mun,
    h16* __restrict__ mu16n, float* __restrict__ q)
{
    const int n = blockIdx.x, f = threadIdx.x;
    half2v fa[12], fb[12], fc[12];
    {
        const half8* pa = (const half8*)(fwt + (size_t)f * 32);
        const half8* pb = (const half8*)(fwt + (size_t)(128 + f) * 32);
#pragma unroll
        for (int r = 0; r < 3; ++r) {
            *(half8*)&fa[r * 4] = pa[r];
            *(half8*)&fb[r * 4] = pb[r];
        }
        if (HAS_MU) {
            const half8* pc = (const half8*)(fwt + (size_t)(256 + f) * 32);
#pragma unroll
            for (int r = 0; r < 3; ++r)
                *(half8*)&fc[r * 4] = pc[r];
        }
    }
    float accq = 0.f, am0 = 0.f, am1 = 0.f, am2 = 0.f;
    const int e0 = row_start[n], e1 = row_start[n + 1];
    for (int e = e0; e < e1; ++e) {
        half2v pr[12];
        const h16* pb8 = ph + (size_t)e * 32;
        *(half8*)&pr[0] = *(const half8*)pb8;
        *(half8*)&pr[4] = *(const half8*)(pb8 + 8);
        *(half8*)&pr[8] = *(const half8*)(pb8 + 16);
        half2v A0 = {(h16)0.f, (h16)0.f}, A1 = A0, A2 = A0;
#pragma unroll
        for (int r = 0; r < 11; ++r) {
            A0 = pr[r] * fa[r] + A0;
            A1 = pr[r] * fb[r] + A1;
            if (HAS_MU) A2 = pr[r] * fc[r] + A2;
        }
        float w0 = (float)A0[0] + (float)A0[1];
        float w1 = (float)A1[0] + (float)A1[1];
        int j = idx_j[e];
        float4 g = *(const float4*)&dir[(size_t)e * 4];
        const h16* xb = x16 + (size_t)j * 384;
        float x0 = (float)xb[f], x1 = (float)xb[128 + f];
        accq = fmaf(w0, x0, accq);
        float xw1 = w1 * x1;
        if (HAS_MU) {
            float w2 = (float)A2[0] + (float)A2[1];
            float x2 = (float)xb[256 + f];
            float xw2 = w2 * x2;
            const h16* mb = mu16p + (size_t)j * 384;
            am0 += xw1 * g.x + xw2 * (float)mb[f];
            am1 += xw1 * g.y + xw2 * (float)mb[128 + f];
            am2 += xw1 * g.z + xw2 * (float)mb[256 + f];
        } else {
            am0 = fmaf(xw1, g.x, am0);
            am1 = fmaf(xw1, g.y, am1);
            am2 = fmaf(xw1, g.z, am2);
        }
    }
    q[(size_t)n * FD + f] += accq;
    size_t b = (size_t)n * 384;
    float m0 = (HAS_MU ? mup[b + f] : 0.f) + am0;
    float m1 = (HAS_MU ? mup[b + 128 + f] : 0.f) + am1;
    float m2 = (HAS_MU ? mup[b + 256 + f] : 0.f) + am2;
    mun[b + f] = m0; mun[b + 128 + f] = m1; mun[b + 256 + f] = m2;
    mu16n[b + f] = (h16)m0; mu16n[b + 128 + f] = (h16)m1; mu16n[b + 256 + f] = (h16)m2;
}

// ====== fused mixing (+ optional next-iteration interaction MLP) ======
__global__ __launch_bounds__(256) void mixint_kernel(
    const h16* __restrict__ mu16n, const h16* __restrict__ WmuT,
    const h16* __restrict__ W1t, const float* __restrict__ b1,
    const h16* __restrict__ W2t, const float* __restrict__ b2,
    float* __restrict__ q, float* __restrict__ mu, h16* __restrict__ mu16w,
    const h16* __restrict__ nW1t, const float* __restrict__ nb1,
    const h16* __restrict__ nW2t, const float* __restrict__ nb2,
    h16* __restrict__ x16)
{
    __shared__ h16 MM[48 * 264];
    __shared__ h16 CT[16 * 264];
    __shared__ h16 Hs[16 * 136];
    __shared__ h16 XM[16 * 392];
    const int tid = threadIdx.x;
    const int wave = tid >> 6, lane = tid & 63;
    const int ar = lane & 15, kg = lane >> 4;
    const size_t row0 = (size_t)blockIdx.x * 16;

    {
        f32x4 acc[3][4] = {};
        int aloc[3], dloc[3];
#pragma unroll
        for (int rt = 0; rt < 3; ++rt) {
            int rr = rt * 16 + ar;
            aloc[rt] = rr / 3;
            dloc[rt] = rr - 3 * aloc[rt];
        }
        for (int ks = 0; ks < 128; ks += 32) {
            int k = ks + kg * 8;
            half8 afr[3];
#pragma unroll
            for (int rt = 0; rt < 3; ++rt)
                afr[rt] = *(const half8*)&mu16n[(row0 + aloc[rt]) * 384 + dloc[rt] * 128 + k];
#pragma unroll
            for (int ct = 0; ct < 4; ++ct) {
                int cc = wave * 4 + ct;
                half8 bf = *(const half8*)&WmuT[(size_t)(cc * 16 + ar) * 128 + k];
#pragma unroll
                for (int rt = 0; rt < 3; ++rt)
                    acc[rt][ct] = __builtin_amdgcn_mfma_f32_16x16x32_f16(afr[rt], bf, acc[rt][ct], 0, 0, 0);
            }
        }
#pragma unroll
        for (int rt = 0; rt < 3; ++rt)
#pragma unroll
            for (int ct = 0; ct < 4; ++ct) {
                int col = (wave * 4 + ct) * 16 + ar;
#pragma unroll
                for (int r = 0; r < 4; ++r)
                    MM[(rt * 16 + kg * 4 + r) * 264 + col] = (h16)acc[rt][ct][r];
            }
    }
    __syncthreads();

    {
        int a = tid >> 4, fi = (tid & 15) * 8;
        const float* qp = q + (row0 + a) * 128 + fi;
        float4 q0 = *(const float4*)qp;
        float4 q1 = *(const float4*)(qp + 4);
        float qv[8] = {q0.x, q0.y, q0.z, q0.w, q1.x, q1.y, q1.z, q1.w};
#pragma unroll
        for (int jj = 0; jj < 8; ++jj) {
            int ff = fi + jj;
            float v0 = (float)MM[(a * 3 + 0) * 264 + ff];
            float v1 = (float)MM[(a * 3 + 1) * 264 + ff];
            float v2 = (float)MM[(a * 3 + 2) * 264 + ff];
            CT[a * 264 + 128 + ff] = (h16)sqrtf(v0 * v0 + v1 * v1 + v2 * v2 + 1e-8f);
            CT[a * 264 + ff] = (h16)qv[jj];
        }
    }
    __syncthreads();

    {
        f32x4 a1[2] = {};
        for (int ks = 0; ks < 256; ks += 32) {
            int k = ks + kg * 8;
            half8 af = *(const half8*)&CT[ar * 264 + k];
#pragma unroll
            for (int tt = 0; tt < 2; ++tt) {
                int t = wave * 2 + tt;
                half8 bf = *(const half8*)&W1t[(size_t)(t * 16 + ar) * 256 + k];
                a1[tt] = __builtin_amdgcn_mfma_f32_16x16x32_f16(af, bf, a1[tt], 0, 0, 0);
            }
        }
#pragma unroll
        for (int tt = 0; tt < 2; ++tt) {
            int col = (wave * 2 + tt) * 16 + ar;
            float bb = b1[col];
#pragma unroll
            for (int r = 0; r < 4; ++r)
                Hs[(kg * 4 + r) * 136 + col] = (h16)silu(a1[tt][r] + bb);
        }
    }
    __syncthreads();

    {
        f32x4 a2[6] = {};
        for (int ks = 0; ks < 128; ks += 32) {
            int k = ks + kg * 8;
            half8 af = *(const half8*)&Hs[ar * 136 + k];
#pragma unroll
            for (int tt = 0; tt < 6; ++tt) {
                int t = wave * 6 + tt;
                half8 bf = *(const half8*)&W2t[(size_t)(t * 16 + ar) * 128 + k];
                a2[tt] = __builtin_amdgcn_mfma_f32_16x16x32_f16(af, bf, a2[tt], 0, 0, 0);
            }
        }
#pragma unroll
        for (int tt = 0; tt < 6; ++tt) {
            int col = (wave * 6 + tt) * 16 + ar;
            float bb = b2[col];
#pragma unroll
            for (int r = 0; r < 4; ++r)
                XM[(kg * 4 + r) * 392 + col] = (h16)(a2[tt][r] + bb);
        }
    }
    __syncthreads();

    {
        int a = tid >> 4, fi = (tid & 15) * 8;
        size_t n = row0 + a;
#pragma unroll
        for (int jj = 0; jj < 8; ++jj) {
            int ff = fi + jj;
            float dq  = (float)XM[a * 392 + ff];
            float dm  = (float)XM[a * 392 + 128 + ff];
            float dqm = (float)XM[a * 392 + 256 + ff];
            float v0 = (float)MM[(a * 3 + 0) * 264 + ff], w0 = (float)MM[(a * 3 + 0) * 264 + 128 + ff];
            float v1 = (float)MM[(a * 3 + 1) * 264 + ff], w1 = (float)MM[(a * 3 + 1) * 264 + 128 + ff];
            float v2 = (float)MM[(a * 3 + 2) * 264 + ff], w2 = (float)MM[(a * 3 + 2) * 264 + 128 + ff];
            float sv = v0 * w0 + v1 * w1 + v2 * w2;
            float qn = q[n * 128 + ff] + dq + dqm * sv;
            q[n * 128 + ff] = qn;
            CT[a * 264 + ff] = (h16)qn;
            size_t b = n * 384 + ff;
            float m0 = mu[b] + dm * w0;
            float m1 = mu[b + 128] + dm * w1;
            float m2 = mu[b + 256] + dm * w2;
            mu[b] = m0; mu[b + 128] = m1; mu[b + 256] = m2;
            mu16w[b] = (h16)m0; mu16w[b + 128] = (h16)m1; mu16w[b + 256] = (h16)m2;
        }
    }
    if (!nW1t) return;
    __syncthreads();

    {
        f32x4 a1[2] = {};
        for (int ks = 0; ks < 128; ks += 32) {
            int k = ks + kg * 8;
            half8 af = *(const half8*)&CT[ar * 264 + k];
#pragma unroll
            for (int tt = 0; tt < 2; ++tt) {
                int t = wave * 2 + tt;
                half8 bf = *(const half8*)&nW1t[(size_t)(t * 16 + ar) * 128 + k];
                a1[tt] = __builtin_amdgcn_mfma_f32_16x16x32_f16(af, bf, a1[tt], 0, 0, 0);
            }
        }
#pragma unroll
        for (int tt = 0; tt < 2; ++tt) {
            int col = (wave * 2 + tt) * 16 + ar;
            float bb = nb1[col];
#pragma unroll
            for (int r = 0; r < 4; ++r)
                Hs[(kg * 4 + r) * 136 + col] = (h16)silu(a1[tt][r] + bb);
        }
        __syncthreads();
        f32x4 a2[6] = {};
        for (int ks = 0; ks < 128; ks += 32) {
            int k = ks + kg * 8;
            half8 af = *(const half8*)&Hs[ar * 136 + k];
#pragma unroll
            for (int tt = 0; tt < 6; ++tt) {
                int t = wave * 6 + tt;
                half8 bf = *(const half8*)&nW2t[(size_t)(t * 16 + ar) * 128 + k];
                a2[tt] = __builtin_amdgcn_mfma_f32_16x16x32_f16(af, bf, a2[tt], 0, 0, 0);
            }
        }
#pragma unroll
        for (int tt = 0; tt < 6; ++tt) {
            int col = (wave * 6 + tt) * 16 + ar;
            float bb = nb2[col];
#pragma unroll
            for (int r = 0; r < 4; ++r)
                x16[(row0 + kg * 4 + r) * 384 + col] = (h16)(a2[tt][r] + bb);
        }
    }
}

// ====== launch ======
extern "C" void kernel_launch(void* const* d_in, const int* in_sizes, int n_in,
                              void* d_out, int out_size, void* d_ws, size_t ws_size,
                              hipStream_t stream)
{
    const int*   Z       = (const int*)d_in[0];
    const float* R       = (const float*)d_in[1];
    const int*   idx_i   = (const int*)d_in[2];
    const int*   idx_j   = (const int*)d_in[3];
    const float* offsets = (const float*)d_in[4];
    const float* emb     = (const float*)d_in[5];
    const float* filt_W  = (const float*)d_in[6];
    const float* filt_b  = (const float*)d_in[7];
    const float* int_W1  = (const float*)d_in[8];
    const float* int_b1  = (const float*)d_in[9];
    const float* int_W2  = (const float*)d_in[10];
    const float* int_b2  = (const float*)d_in[11];
    const float* mix_Wmu = (const float*)d_in[12];
    const float* mix_W1  = (const float*)d_in[13];
    const float* mix_b1  = (const float*)d_in[14];
    const float* mix_W2  = (const float*)d_in[15];
    const float* mix_b2  = (const float*)d_in[16];

    float* q_out  = (float*)d_out;
    float* mu_out = (float*)d_out + (size_t)NA * FD;

    char* base = (char*)d_ws;
    size_t o = 0;
    auto alloc = [&](size_t bytes) -> void* {
        void* p = base + o;
        o += (bytes + 255) & ~(size_t)255;
        return p;
    };
    float* dir    = (float*)alloc((size_t)NE * 4 * 4);
    h16*   ph     = (h16*)alloc((size_t)NE * 32 * 2);
    h16*   x16    = (h16*)alloc((size_t)NA * 384 * 2);
    h16*   mu16a  = (h16*)alloc((size_t)NA * 384 * 2);
    h16*   mu16b  = (h16*)alloc((size_t)NA * 384 * 2);
    float* mu_ws  = (float*)alloc((size_t)NA * 384 * 4);
    h16*   W1t    = (h16*)alloc((size_t)3 * 128 * 128 * 2);
    h16*   W2t    = (h16*)alloc((size_t)3 * 384 * 128 * 2);
    h16*   WmuT   = (h16*)alloc((size_t)3 * 256 * 128 * 2);
    h16*   mW1t   = (h16*)alloc((size_t)3 * 128 * 256 * 2);
    h16*   mW2t   = (h16*)alloc((size_t)3 * 384 * 128 * 2);
    h16*   fwt    = (h16*)alloc((size_t)384 * 32 * 2);
    int*   row_st = (int*)alloc((size_t)(NA + 1) * 4);

    setup_kernel<<<3177, 256, 0, stream>>>(R, idx_i, idx_j, offsets, dir, ph, row_st,
                                           int_W1, int_W2, mix_Wmu, mix_W1, mix_W2,
                                           W1t, W2t, WmuT, mW1t, mW2t,
                                           filt_W, filt_b, fwt);

    // iteration 0
    intmlp0_kernel<<<NA / 16, 256, 0, stream>>>(Z, emb, q_out,
                                                W1t, int_b1, W2t, int_b2, x16);
    edge_kernel<false><<<NA, 128, 0, stream>>>(dir, ph, fwt, row_st, idx_j,
                                               x16, nullptr, nullptr, mu_out, mu16b, q_out);
    mixint_kernel<<<NA / 16, 256, 0, stream>>>(
        mu16b, WmuT, mW1t, mix_b1, mW2t, mix_b2, q_out, mu_out, mu16b,
        W1t + 16384, int_b1 + 128, W2t + 49152, int_b2 + 384, x16);

    // iteration 1
    edge_kernel<true><<<NA, 128, 0, stream>>>(dir, ph, fwt, row_st, idx_j,
                                              x16, mu16b, mu_out, mu_ws, mu16a, q_out);
    mixint_kernel<<<NA / 16, 256, 0, stream>>>(
        mu16a, WmuT + 32768, mW1t + 32768, mix_b1 + 128, mW2t + 49152, mix_b2 + 384,
        q_out, mu_ws, mu16a,
        W1t + 32768, int_b1 + 256, W2t + 98304, int_b2 + 768, x16);

    // iteration 2
    edge_kernel<true><<<NA, 128, 0, stream>>>(dir, ph, fwt, row_st, idx_j,
                                              x16, mu16a, mu_ws, mu_out, mu16b, q_out);
    mixint_kernel<<<NA / 16, 256, 0, stream>>>(
        mu16b, WmuT + 65536, mW1t + 65536, mix_b1 + 256, mW2t + 98304, mix_b2 + 768,
        q_out, mu_out, mu16b,
        nullptr, nullptr, nullptr, nullptr, nullptr);
}